// Round 3
// baseline (371.797 us; speedup 1.0000x reference)
//
#include <hip/hip_runtime.h>
#include <hip/hip_bf16.h>
#include <stdint.h>

typedef __attribute__((ext_vector_type(4))) float f32x4;
typedef __attribute__((ext_vector_type(8))) short bf16x8;

#define BK 64

__device__ inline void gload_lds16(const void* g, void* l) {
    __builtin_amdgcn_global_load_lds(
        (const __attribute__((address_space(1))) void*)g,
        (__attribute__((address_space(3))) void*)l, 16, 0, 0);
}

// bijective XCD swizzle (m204)
__device__ inline int xcd_swizzle(int orig, int nwg) {
    int q = nwg >> 3, r = nwg & 7;
    int xcd = orig & 7, idx = orig >> 3;
    int base = (xcd < r) ? xcd * (q + 1) : r * (q + 1) + (xcd - r) * q;
    return base + idx;
}

// Convert features fp32 [16384][2144] -> bf16 [16384][2176] (zero padded)
__global__ __launch_bounds__(256) void cvt_feat(const float* __restrict__ in,
                                                __hip_bfloat16* __restrict__ out) {
    int i = blockIdx.x * 256 + threadIdx.x;
    const int CH = 16384 * 272;
    if (i >= CH) return;
    int r = i / 272, c8 = (i % 272) * 8;
    __hip_bfloat16 tmp[8];
    if (c8 < 2144) {
        const float4* p = (const float4*)(in + (size_t)r * 2144 + c8);
        float4 x0 = p[0], x1 = p[1];
        tmp[0] = __float2bfloat16(x0.x); tmp[1] = __float2bfloat16(x0.y);
        tmp[2] = __float2bfloat16(x0.z); tmp[3] = __float2bfloat16(x0.w);
        tmp[4] = __float2bfloat16(x1.x); tmp[5] = __float2bfloat16(x1.y);
        tmp[6] = __float2bfloat16(x1.z); tmp[7] = __float2bfloat16(x1.w);
    } else {
        #pragma unroll
        for (int j = 0; j < 8; j++) tmp[j] = __float2bfloat16(0.f);
    }
    *(bf16x8*)&out[(size_t)r * 2176 + c8] = *(const bf16x8*)tmp;
}

// WT[n][k] = bf16(W[k][n]), zero-padded k in [K, KP)
__global__ __launch_bounds__(256) void cvt_wt(const float* __restrict__ W,
                                              __hip_bfloat16* __restrict__ WT,
                                              int K, int N, int KP) {
    int idx = blockIdx.x * 256 + threadIdx.x;
    if (idx >= N * KP) return;
    int n = idx / KP, k = idx % KP;
    WT[idx] = (k < K) ? __float2bfloat16(W[(size_t)k * N + n]) : __float2bfloat16(0.f);
}

// 2-phase double-buffered GEMM (T3/T4-lite): BM=256 x BN_ tile, 8 waves (2Mx4N),
// stage(t+1) issued BEFORE compute(t); ONE barrier per K-tile.
// RES_MODE: 0 none, 1 full res[M][N], 2 broadcast res[row>>5][N]
template<int BN_, int RES_MODE, bool OUT_BF16, bool OUT_F32>
__global__ __launch_bounds__(512, 2)
void gemm2ph(const __hip_bfloat16* __restrict__ A, int lda,
             const __hip_bfloat16* __restrict__ Bt,
             const float* __restrict__ bias,
             const float* __restrict__ res,
             __hip_bfloat16* __restrict__ outb,
             float* __restrict__ outf,
             int M, int N, int K, int gx)
{
    constexpr int NF = BN_ / 64;            // B frags per wave (4 or 2)
    constexpr int BR = BN_ / 64;            // B staging rounds (64 rows each)
    __shared__ __hip_bfloat16 lA[2][256 * BK];
    __shared__ __hip_bfloat16 lB[2][BN_ * BK];

    const int nwg  = gridDim.x;
    const int wgid = xcd_swizzle(blockIdx.x, nwg);
    const int by   = wgid / gx;
    const int bx   = wgid - by * gx;

    const int t    = threadIdx.x;
    const int lane = t & 63;
    const int wv   = t >> 6;                // 8 waves
    const int wr   = wv >> 2;               // 0..1 (128-row half)
    const int wc   = wv & 3;                // 0..3 (BN_/4-wide col strip)

    const int row0 = by * 256;
    const int col0 = bx * BN_;

    // split-K (gridDim.y splits; partials at outf + split*M*N when >1)
    const int NT = K / BK;
    const int split = blockIdx.y;
    const int kb = (split * NT) / gridDim.y;
    const int ke = ((split + 1) * NT) / gridDim.y;
    if (OUT_F32 && gridDim.y > 1) outf += (size_t)split * M * N;

    const int srow = t >> 3;                // 0..63
    const int scol = (t & 7) * 8;

    f32x4 acc[8][NF];
    #pragma unroll
    for (int i = 0; i < 8; i++)
        #pragma unroll
        for (int j = 0; j < NF; j++)
            acc[i][j] = f32x4{0.f, 0.f, 0.f, 0.f};

    const int lrow = lane & 15;
    const int lk   = (lane >> 4) * 8;

    auto stage = [&](int buf, int kt) {
        const int k0 = kt * BK;
        #pragma unroll
        for (int r = 0; r < 4; ++r)
            gload_lds16(A + (size_t)(row0 + r * 64 + srow) * lda + k0 + scol,
                        &lA[buf][(r * 64 + srow) * BK + scol]);
        #pragma unroll
        for (int r = 0; r < BR; ++r)
            gload_lds16(Bt + (size_t)(col0 + r * 64 + srow) * K + k0 + scol,
                        &lB[buf][(r * 64 + srow) * BK + scol]);
    };

    auto compute = [&](int buf) {
        #pragma unroll
        for (int kk = 0; kk < BK; kk += 32) {
            bf16x8 bg[NF];
            #pragma unroll
            for (int j = 0; j < NF; j++)
                bg[j] = *(const bf16x8*)&lB[buf][(wc * NF * 16 + j * 16 + lrow) * BK + kk + lk];
            #pragma unroll
            for (int i = 0; i < 8; i++) {
                bf16x8 af = *(const bf16x8*)&lA[buf][(wr * 128 + i * 16 + lrow) * BK + kk + lk];
                #pragma unroll
                for (int j = 0; j < NF; j++)
                    acc[i][j] = __builtin_amdgcn_mfma_f32_16x16x32_bf16(af, bg[j], acc[i][j], 0, 0, 0);
            }
        }
    };

    int cur = 0;
    stage(0, kb);
    __syncthreads();                         // drains vmcnt(0): tile kb ready
    for (int kt = kb; kt < ke - 1; ++kt) {
        stage(cur ^ 1, kt + 1);              // issue next-tile loads first
        compute(cur);                        // overlap: MFMA hides load latency
        __syncthreads();                     // next tile ready, prev reads retired
        cur ^= 1;
    }
    compute(cur);

    // epilogue: C/D layout col=lane&15, row=(lane>>4)*4+reg
    #pragma unroll
    for (int j = 0; j < NF; j++) {
        const int col = col0 + wc * NF * 16 + j * 16 + lrow;
        const float bv = bias ? bias[col] : 0.f;
        #pragma unroll
        for (int i = 0; i < 8; i++) {
            const int rbase = row0 + wr * 128 + i * 16 + (lane >> 4) * 4;
            #pragma unroll
            for (int r = 0; r < 4; r++) {
                const int row = rbase + r;
                float v = acc[i][j][r] + bv;
                if (RES_MODE == 1) v += res[(size_t)row * N + col];
                if (RES_MODE == 2) v += res[(size_t)(row >> 5) * N + col];
                if (OUT_F32) outf[(size_t)row * N + col] = v;
                if (OUT_BF16) {
                    float lv = v >= 0.f ? v : 0.01f * v;
                    outb[(size_t)row * N + col] = __float2bfloat16(lv);
                }
            }
        }
    }
}

// eanchor = sum of 8 split-K partials + be
__global__ __launch_bounds__(256)
void anchor_reduce(const float* __restrict__ part, const float* __restrict__ be,
                   float* __restrict__ out) {
    int i = blockIdx.x * 256 + threadIdx.x;     // 512*1024 elements
    if (i >= 512 * 1024) return;
    const int S = 512 * 1024;
    int col = i & 1023;
    float s = be[col];
    #pragma unroll
    for (int p = 0; p < 8; p++) s += part[i + p * S];
    out[i] = s;
}

// out[row] = leaky(h[row]) @ Wd + bd + [0,0,1], fp32, one wave per row
__global__ __launch_bounds__(256)
void final_head(const float* __restrict__ h, const float* __restrict__ Wd,
                const float* __restrict__ bd, float* __restrict__ out)
{
    int row  = blockIdx.x * 4 + (threadIdx.x >> 6);
    int lane = threadIdx.x & 63;
    const float* hr = h + (size_t)row * 512;
    float s0 = 0.f, s1 = 0.f, s2 = 0.f;
    #pragma unroll
    for (int j = 0; j < 8; j++) {
        int k = j * 64 + lane;
        float v = hr[k];
        v = v >= 0.f ? v : 0.01f * v;
        s0 += v * Wd[k * 3 + 0];
        s1 += v * Wd[k * 3 + 1];
        s2 += v * Wd[k * 3 + 2];
    }
    #pragma unroll
    for (int off = 32; off > 0; off >>= 1) {
        s0 += __shfl_down(s0, off);
        s1 += __shfl_down(s1, off);
        s2 += __shfl_down(s2, off);
    }
    if (lane == 0) {
        out[row * 3 + 0] = s0 + bd[0];
        out[row * 3 + 1] = s1 + bd[1];
        out[row * 3 + 2] = s2 + bd[2] + 1.0f;
    }
}

extern "C" void kernel_launch(void* const* d_in, const int* in_sizes, int n_in,
                              void* d_out, int out_size, void* d_ws, size_t ws_size,
                              hipStream_t stream)
{
    const float* features = (const float*)d_in[0];
    const float* We  = (const float*)d_in[1];
    const float* be  = (const float*)d_in[2];
    const float* W1a = (const float*)d_in[3];
    const float* b1a = (const float*)d_in[4];
    const float* W1b = (const float*)d_in[5];
    const float* b1b = (const float*)d_in[6];
    const float* W2a = (const float*)d_in[7];
    const float* b2a = (const float*)d_in[8];
    const float* W2b = (const float*)d_in[9];
    const float* b2b = (const float*)d_in[10];
    const float* Wd  = (const float*)d_in[11];
    const float* bd  = (const float*)d_in[12];
    float* out = (float*)d_out;

    char* ws = (char*)d_ws;
    size_t off = 0;
    auto alloc = [&](size_t bytes) -> char* {
        char* p = ws + off;
        off += (bytes + 255) & ~(size_t)255;
        return p;
    };
    __hip_bfloat16* featbf = (__hip_bfloat16*)alloc(16384ull * 2176 * 2);
    __hip_bfloat16* WeTt   = (__hip_bfloat16*)alloc(1024ull * 2176 * 2);
    __hip_bfloat16* WeTb   = (__hip_bfloat16*)alloc(1024ull * 2176 * 2);
    __hip_bfloat16* W1aT   = (__hip_bfloat16*)alloc(1024ull * 1024 * 2);
    __hip_bfloat16* W1bT   = (__hip_bfloat16*)alloc(512ull * 1024 * 2);
    __hip_bfloat16* W2aT   = (__hip_bfloat16*)alloc(512ull * 512 * 2);
    __hip_bfloat16* W2bT   = (__hip_bfloat16*)alloc(512ull * 512 * 2);
    float* eanchor_part    = (float*)alloc(8ull * 512 * 1024 * 4);
    float* eanchor         = (float*)alloc(512ull * 1024 * 4);
    char* bufA             = alloc(16384ull * 1024 * 2);
    char* bufB             = alloc(16384ull * 1024 * 2);
    float* h1              = (float*)alloc(16384ull * 512 * 4);

    __hip_bfloat16* act1 = (__hip_bfloat16*)bufA;
    __hip_bfloat16* act2 = (__hip_bfloat16*)bufB;
    __hip_bfloat16* act3 = (__hip_bfloat16*)bufA;
    __hip_bfloat16* act4 = (__hip_bfloat16*)bufB;
    float*          hsum = (float*)bufA;

    // ---- converts ----
    cvt_feat<<<(16384 * 272 + 255) / 256, 256, 0, stream>>>(features, featbf);
    cvt_wt<<<(1024 * 2176 + 255) / 256, 256, 0, stream>>>(We,              WeTt, 2144, 1024, 2176);
    cvt_wt<<<(1024 * 2176 + 255) / 256, 256, 0, stream>>>(We + 2144 * 1024, WeTb, 2144, 1024, 2176);
    cvt_wt<<<(1024 * 1024 + 255) / 256, 256, 0, stream>>>(W1a, W1aT, 1024, 1024, 1024);
    cvt_wt<<<(512 * 1024 + 255) / 256, 256, 0, stream>>>(W1b, W1bT, 1024, 512, 1024);
    cvt_wt<<<(512 * 512 + 255) / 256, 256, 0, stream>>>(W2a, W2aT, 512, 512, 512);
    cvt_wt<<<(512 * 512 + 255) / 256, 256, 0, stream>>>(W2b, W2bT, 512, 512, 512);

    // ---- anchor GEMM (split-K=8): partials = feat_row(b*32) @ We[2144:,:] ----
    gemm2ph<256, 0, false, true><<<dim3(8, 8), 512, 0, stream>>>(
        featbf, 32 * 2176, WeTb, nullptr, nullptr, nullptr, eanchor_part,
        512, 1024, 2176, 4);
    anchor_reduce<<<2048, 256, 0, stream>>>(eanchor_part, be, eanchor);

    // ---- L1: act1 = bf16(leaky(feat @ We[:2144,:] + eanchor_bcast)) ----
    gemm2ph<256, 2, true, false><<<dim3(256), 512, 0, stream>>>(
        featbf, 2176, WeTt, nullptr, eanchor, act1, nullptr, 16384, 1024, 2176, 4);

    // ---- L2: act2 = bf16(leaky(act1 @ W1a + b1a)) ----
    gemm2ph<256, 0, true, false><<<dim3(256), 512, 0, stream>>>(
        act1, 1024, W1aT, b1a, nullptr, act2, nullptr, 16384, 1024, 1024, 4);

    // ---- L3: h1 = act2 @ W1b + b1b (fp32), act3 = bf16(leaky(h1)) ----
    gemm2ph<128, 0, true, true><<<dim3(256), 512, 0, stream>>>(
        act2, 1024, W1bT, b1b, nullptr, act3, h1, 16384, 512, 1024, 4);

    // ---- L4: act4 = bf16(leaky(act3 @ W2a + b2a)) ----
    gemm2ph<128, 0, true, false><<<dim3(256), 512, 0, stream>>>(
        act3, 512, W2aT, b2a, nullptr, act4, nullptr, 16384, 512, 512, 4);

    // ---- L5: hsum = act4 @ W2b + b2b + h1 (fp32) ----
    gemm2ph<128, 1, false, true><<<dim3(256), 512, 0, stream>>>(
        act4, 512, W2bT, b2b, h1, nullptr, hsum, 16384, 512, 512, 4);

    // ---- head ----
    final_head<<<4096, 256, 0, stream>>>(hsum, Wd, bd, out);
}

// Round 4
// 300.146 us; speedup vs baseline: 1.2387x; 1.2387x over previous
//
#include <hip/hip_runtime.h>
#include <hip/hip_bf16.h>
#include <stdint.h>

typedef __attribute__((ext_vector_type(4))) float f32x4;
typedef __attribute__((ext_vector_type(8))) short bf16x8;

#define BK 64

__device__ inline void gload_lds16(const void* g, void* l) {
    __builtin_amdgcn_global_load_lds(
        (const __attribute__((address_space(1))) void*)g,
        (__attribute__((address_space(3))) void*)l, 16, 0, 0);
}

// bijective XCD swizzle (m204)
__device__ inline int xcd_swizzle(int orig, int nwg) {
    int q = nwg >> 3, r = nwg & 7;
    int xcd = orig & 7, idx = orig >> 3;
    int base = (xcd < r) ? xcd * (q + 1) : r * (q + 1) + (xcd - r) * q;
    return base + idx;
}

// Convert features fp32 [16384][2144] -> bf16 [16384][2176] (zero padded)
__global__ __launch_bounds__(256) void cvt_feat(const float* __restrict__ in,
                                                __hip_bfloat16* __restrict__ out) {
    int i = blockIdx.x * 256 + threadIdx.x;
    const int CH = 16384 * 272;
    if (i >= CH) return;
    int r = i / 272, c8 = (i % 272) * 8;
    __hip_bfloat16 tmp[8];
    if (c8 < 2144) {
        const float4* p = (const float4*)(in + (size_t)r * 2144 + c8);
        float4 x0 = p[0], x1 = p[1];
        tmp[0] = __float2bfloat16(x0.x); tmp[1] = __float2bfloat16(x0.y);
        tmp[2] = __float2bfloat16(x0.z); tmp[3] = __float2bfloat16(x0.w);
        tmp[4] = __float2bfloat16(x1.x); tmp[5] = __float2bfloat16(x1.y);
        tmp[6] = __float2bfloat16(x1.z); tmp[7] = __float2bfloat16(x1.w);
    } else {
        #pragma unroll
        for (int j = 0; j < 8; j++) tmp[j] = __float2bfloat16(0.f);
    }
    *(bf16x8*)&out[(size_t)r * 2176 + c8] = *(const bf16x8*)tmp;
}

// Tiled transpose: WT[n][kp] = bf16(W[k][n]), zero pad kp in [K,KP). KP,N mult of 32.
__global__ __launch_bounds__(256) void cvt_wt_t(const float* __restrict__ W,
                                                __hip_bfloat16* __restrict__ WT,
                                                int K, int N, int KP) {
    __shared__ float tile[32][33];
    const int ntn = N >> 5;
    const int tk = blockIdx.x / ntn, tn = blockIdx.x - tk * ntn;
    const int k0 = tk * 32, n0 = tn * 32;
    const int c = threadIdx.x & 31, r8 = threadIdx.x >> 5;
    #pragma unroll
    for (int p = 0; p < 4; p++) {
        int k = k0 + r8 + p * 8;
        tile[r8 + p * 8][c] = (k < K) ? W[(size_t)k * N + n0 + c] : 0.f;
    }
    __syncthreads();
    #pragma unroll
    for (int p = 0; p < 4; p++) {
        int n = n0 + r8 + p * 8;
        WT[(size_t)n * KP + k0 + c] = __float2bfloat16(tile[c][r8 + p * 8]);
    }
}

// 2-phase double-buffered GEMM, T2 XOR-swizzled LDS (both-sides: inverse-swz
// global source at staging, swz ds_read), T5 setprio around MFMA cluster.
// BM=256 x BN_ tile, 8 waves (2Mx4N). RES_MODE: 0 none, 1 full, 2 row>>5 bcast.
template<int BN_, int RES_MODE, bool OUT_BF16, bool OUT_F32>
__global__ __launch_bounds__(512, 2)
void gemm2ph(const __hip_bfloat16* __restrict__ A, int lda,
             const __hip_bfloat16* __restrict__ Bt,
             const float* __restrict__ bias,
             const float* __restrict__ res,
             __hip_bfloat16* __restrict__ outb,
             float* __restrict__ outf,
             int M, int N, int K, int gx)
{
    constexpr int NF = BN_ / 64;            // B frags per wave
    constexpr int BR = BN_ / 64;            // B staging rounds (64 rows each)
    __shared__ __hip_bfloat16 lA[2][256 * BK];
    __shared__ __hip_bfloat16 lB[2][BN_ * BK];

    const int nwg  = gridDim.x;
    const int wgid = xcd_swizzle(blockIdx.x, nwg);
    const int by   = wgid / gx;
    const int bx   = wgid - by * gx;

    const int t    = threadIdx.x;
    const int lane = t & 63;
    const int wv   = t >> 6;
    const int wr   = wv >> 2;               // 0..1
    const int wc   = wv & 3;                // 0..3

    const int row0 = by * 256;
    const int col0 = bx * BN_;

    const int NT = K / BK;
    const int split = blockIdx.y;
    const int kb = (split * NT) / gridDim.y;
    const int ke = ((split + 1) * NT) / gridDim.y;
    if (OUT_F32 && gridDim.y > 1) outf += (size_t)split * M * N;

    const int srow = t >> 3;                // 0..63
    const int scol = ((t & 7) * 8) ^ ((srow & 7) << 3);  // inverse-swizzled source col
    const int sdst = (t & 7) * 8;                         // linear LDS dest col

    f32x4 acc[8][NF];
    #pragma unroll
    for (int i = 0; i < 8; i++)
        #pragma unroll
        for (int j = 0; j < NF; j++)
            acc[i][j] = f32x4{0.f, 0.f, 0.f, 0.f};

    const int lrow = lane & 15;
    const int lk   = (lane >> 4) * 8;
    const int rxor = (lrow & 7) << 3;       // read-side swizzle term (elements)

    auto stage = [&](int buf, int kt) {
        const int k0 = kt * BK;
        #pragma unroll
        for (int r = 0; r < 4; ++r)
            gload_lds16(A + (size_t)(row0 + r * 64 + srow) * lda + k0 + scol,
                        &lA[buf][(r * 64 + srow) * BK + sdst]);
        #pragma unroll
        for (int r = 0; r < BR; ++r)
            gload_lds16(Bt + (size_t)(col0 + r * 64 + srow) * K + k0 + scol,
                        &lB[buf][(r * 64 + srow) * BK + sdst]);
    };

    auto compute = [&](int buf) {
        __builtin_amdgcn_s_setprio(1);
        #pragma unroll
        for (int kk = 0; kk < BK; kk += 32) {
            const int kc = (kk + lk) ^ rxor;
            bf16x8 bg[NF];
            #pragma unroll
            for (int j = 0; j < NF; j++)
                bg[j] = *(const bf16x8*)&lB[buf][(wc * NF * 16 + j * 16 + lrow) * BK + kc];
            #pragma unroll
            for (int i = 0; i < 8; i++) {
                bf16x8 af = *(const bf16x8*)&lA[buf][(wr * 128 + i * 16 + lrow) * BK + kc];
                #pragma unroll
                for (int j = 0; j < NF; j++)
                    acc[i][j] = __builtin_amdgcn_mfma_f32_16x16x32_bf16(af, bg[j], acc[i][j], 0, 0, 0);
            }
        }
        __builtin_amdgcn_s_setprio(0);
    };

    int cur = 0;
    stage(0, kb);
    __syncthreads();
    for (int kt = kb; kt < ke - 1; ++kt) {
        stage(cur ^ 1, kt + 1);
        compute(cur);
        __syncthreads();
        cur ^= 1;
    }
    compute(cur);

    // epilogue: C/D layout col=lane&15, row=(lane>>4)*4+reg
    #pragma unroll
    for (int j = 0; j < NF; j++) {
        const int col = col0 + wc * NF * 16 + j * 16 + lrow;
        const float bv = bias ? bias[col] : 0.f;
        #pragma unroll
        for (int i = 0; i < 8; i++) {
            const int rbase = row0 + wr * 128 + i * 16 + (lane >> 4) * 4;
            #pragma unroll
            for (int r = 0; r < 4; r++) {
                const int row = rbase + r;
                float v = acc[i][j][r] + bv;
                if (RES_MODE == 1) v += res[(size_t)row * N + col];
                if (RES_MODE == 2) v += res[(size_t)(row >> 5) * N + col];
                if (OUT_F32) outf[(size_t)row * N + col] = v;
                if (OUT_BF16) {
                    float lv = v >= 0.f ? v : 0.01f * v;
                    outb[(size_t)row * N + col] = __float2bfloat16(lv);
                }
            }
        }
    }
}

// eanchor = sum of 8 split-K partials + be
__global__ __launch_bounds__(256)
void anchor_reduce(const float* __restrict__ part, const float* __restrict__ be,
                   float* __restrict__ out) {
    int i = blockIdx.x * 256 + threadIdx.x;
    if (i >= 512 * 1024) return;
    const int S = 512 * 1024;
    int col = i & 1023;
    float s = be[col];
    #pragma unroll
    for (int p = 0; p < 8; p++) s += part[i + p * S];
    out[i] = s;
}

// out[row] = leaky(h[row]) @ Wd + bd + [0,0,1]
__global__ __launch_bounds__(256)
void final_head(const float* __restrict__ h, const float* __restrict__ Wd,
                const float* __restrict__ bd, float* __restrict__ out)
{
    int row  = blockIdx.x * 4 + (threadIdx.x >> 6);
    int lane = threadIdx.x & 63;
    const float* hr = h + (size_t)row * 512;
    float s0 = 0.f, s1 = 0.f, s2 = 0.f;
    #pragma unroll
    for (int j = 0; j < 8; j++) {
        int k = j * 64 + lane;
        float v = hr[k];
        v = v >= 0.f ? v : 0.01f * v;
        s0 += v * Wd[k * 3 + 0];
        s1 += v * Wd[k * 3 + 1];
        s2 += v * Wd[k * 3 + 2];
    }
    #pragma unroll
    for (int off = 32; off > 0; off >>= 1) {
        s0 += __shfl_down(s0, off);
        s1 += __shfl_down(s1, off);
        s2 += __shfl_down(s2, off);
    }
    if (lane == 0) {
        out[row * 3 + 0] = s0 + bd[0];
        out[row * 3 + 1] = s1 + bd[1];
        out[row * 3 + 2] = s2 + bd[2] + 1.0f;
    }
}

extern "C" void kernel_launch(void* const* d_in, const int* in_sizes, int n_in,
                              void* d_out, int out_size, void* d_ws, size_t ws_size,
                              hipStream_t stream)
{
    const float* features = (const float*)d_in[0];
    const float* We  = (const float*)d_in[1];
    const float* be  = (const float*)d_in[2];
    const float* W1a = (const float*)d_in[3];
    const float* b1a = (const float*)d_in[4];
    const float* W1b = (const float*)d_in[5];
    const float* b1b = (const float*)d_in[6];
    const float* W2a = (const float*)d_in[7];
    const float* b2a = (const float*)d_in[8];
    const float* W2b = (const float*)d_in[9];
    const float* b2b = (const float*)d_in[10];
    const float* Wd  = (const float*)d_in[11];
    const float* bd  = (const float*)d_in[12];
    float* out = (float*)d_out;

    char* ws = (char*)d_ws;
    size_t off = 0;
    auto alloc = [&](size_t bytes) -> char* {
        char* p = ws + off;
        off += (bytes + 255) & ~(size_t)255;
        return p;
    };
    __hip_bfloat16* featbf = (__hip_bfloat16*)alloc(16384ull * 2176 * 2);
    __hip_bfloat16* WeTt   = (__hip_bfloat16*)alloc(1024ull * 2176 * 2);
    __hip_bfloat16* WeTb   = (__hip_bfloat16*)alloc(1024ull * 2176 * 2);
    __hip_bfloat16* W1aT   = (__hip_bfloat16*)alloc(1024ull * 1024 * 2);
    __hip_bfloat16* W1bT   = (__hip_bfloat16*)alloc(512ull * 1024 * 2);
    __hip_bfloat16* W2aT   = (__hip_bfloat16*)alloc(512ull * 512 * 2);
    __hip_bfloat16* W2bT   = (__hip_bfloat16*)alloc(512ull * 512 * 2);
    float* eanchor_part    = (float*)alloc(8ull * 512 * 1024 * 4);
    float* eanchor         = (float*)alloc(512ull * 1024 * 4);
    char* bufA             = alloc(16384ull * 1024 * 2);
    char* bufB             = alloc(16384ull * 1024 * 2);
    float* h1              = (float*)alloc(16384ull * 512 * 4);

    __hip_bfloat16* act1 = (__hip_bfloat16*)bufA;
    __hip_bfloat16* act2 = (__hip_bfloat16*)bufB;
    __hip_bfloat16* act3 = (__hip_bfloat16*)bufA;
    __hip_bfloat16* act4 = (__hip_bfloat16*)bufB;
    float*          hsum = (float*)bufA;

    // ---- converts ----
    cvt_feat<<<(16384 * 272 + 255) / 256, 256, 0, stream>>>(features, featbf);
    cvt_wt_t<<<68 * 32, 256, 0, stream>>>(We,               WeTt, 2144, 1024, 2176);
    cvt_wt_t<<<68 * 32, 256, 0, stream>>>(We + 2144 * 1024, WeTb, 2144, 1024, 2176);
    cvt_wt_t<<<32 * 32, 256, 0, stream>>>(W1a, W1aT, 1024, 1024, 1024);
    cvt_wt_t<<<32 * 16, 256, 0, stream>>>(W1b, W1bT, 1024, 512, 1024);
    cvt_wt_t<<<16 * 16, 256, 0, stream>>>(W2a, W2aT, 512, 512, 512);
    cvt_wt_t<<<16 * 16, 256, 0, stream>>>(W2b, W2bT, 512, 512, 512);

    // ---- anchor GEMM (split-K=8) ----
    gemm2ph<256, 0, false, true><<<dim3(8, 8), 512, 0, stream>>>(
        featbf, 32 * 2176, WeTb, nullptr, nullptr, nullptr, eanchor_part,
        512, 1024, 2176, 4);
    anchor_reduce<<<2048, 256, 0, stream>>>(eanchor_part, be, eanchor);

    // ---- L1 ----
    gemm2ph<256, 2, true, false><<<dim3(256), 512, 0, stream>>>(
        featbf, 2176, WeTt, nullptr, eanchor, act1, nullptr, 16384, 1024, 2176, 4);

    // ---- L2 ----
    gemm2ph<256, 0, true, false><<<dim3(256), 512, 0, stream>>>(
        act1, 1024, W1aT, b1a, nullptr, act2, nullptr, 16384, 1024, 1024, 4);

    // ---- L3 ----
    gemm2ph<128, 0, true, true><<<dim3(256), 512, 0, stream>>>(
        act2, 1024, W1bT, b1b, nullptr, act3, h1, 16384, 512, 1024, 4);

    // ---- L4 ----
    gemm2ph<128, 0, true, false><<<dim3(256), 512, 0, stream>>>(
        act3, 512, W2aT, b2a, nullptr, act4, nullptr, 16384, 512, 512, 4);

    // ---- L5 ----
    gemm2ph<128, 1, false, true><<<dim3(256), 512, 0, stream>>>(
        act4, 512, W2bT, b2b, h1, nullptr, hsum, 16384, 512, 512, 4);

    // ---- head ----
    final_head<<<4096, 256, 0, stream>>>(hsum, Wd, bd, out);
}

// Round 5
// 256.169 us; speedup vs baseline: 1.4514x; 1.1717x over previous
//
#include <hip/hip_runtime.h>
#include <hip/hip_bf16.h>
#include <stdint.h>

typedef __attribute__((ext_vector_type(4))) float f32x4;
typedef __attribute__((ext_vector_type(8))) short bf16x8;

#define BK 64

__device__ inline void gload_lds16(const void* g, void* l) {
    __builtin_amdgcn_global_load_lds(
        (const __attribute__((address_space(1))) void*)g,
        (__attribute__((address_space(3))) void*)l, 16, 0, 0);
}

// bijective XCD swizzle (m204)
__device__ inline int xcd_swizzle(int orig, int nwg) {
    int q = nwg >> 3, r = nwg & 7;
    int xcd = orig & 7, idx = orig >> 3;
    int base = (xcd < r) ? xcd * (q + 1) : r * (q + 1) + (xcd - r) * q;
    return base + idx;
}

__device__ inline float b2f(short s) {
    union { float f; unsigned u; } x; x.u = ((unsigned)(unsigned short)s) << 16; return x.f;
}
__device__ inline short f2bs(float f) {
    __hip_bfloat16 h = __float2bfloat16(f);
    short s; __builtin_memcpy(&s, &h, 2); return s;
}

// Convert features fp32 [16384][2144] -> bf16 [16384][2176] (zero padded)
__global__ __launch_bounds__(256) void cvt_feat(const float* __restrict__ in,
                                                __hip_bfloat16* __restrict__ out) {
    int i = blockIdx.x * 256 + threadIdx.x;
    const int CH = 16384 * 272;
    if (i >= CH) return;
    int r = i / 272, c8 = (i % 272) * 8;
    __hip_bfloat16 tmp[8];
    if (c8 < 2144) {
        const float4* p = (const float4*)(in + (size_t)r * 2144 + c8);
        float4 x0 = p[0], x1 = p[1];
        tmp[0] = __float2bfloat16(x0.x); tmp[1] = __float2bfloat16(x0.y);
        tmp[2] = __float2bfloat16(x0.z); tmp[3] = __float2bfloat16(x0.w);
        tmp[4] = __float2bfloat16(x1.x); tmp[5] = __float2bfloat16(x1.y);
        tmp[6] = __float2bfloat16(x1.z); tmp[7] = __float2bfloat16(x1.w);
    } else {
        #pragma unroll
        for (int j = 0; j < 8; j++) tmp[j] = __float2bfloat16(0.f);
    }
    *(bf16x8*)&out[(size_t)r * 2176 + c8] = *(const bf16x8*)tmp;
}

// Tiled transpose: WT[n][kp] = bf16(W[k][n]), zero pad kp in [K,KP).
__global__ __launch_bounds__(256) void cvt_wt_t(const float* __restrict__ W,
                                                __hip_bfloat16* __restrict__ WT,
                                                int K, int N, int KP) {
    __shared__ float tile[32][33];
    const int ntn = N >> 5;
    const int tk = blockIdx.x / ntn, tn = blockIdx.x - tk * ntn;
    const int k0 = tk * 32, n0 = tn * 32;
    const int c = threadIdx.x & 31, r8 = threadIdx.x >> 5;
    #pragma unroll
    for (int p = 0; p < 4; p++) {
        int k = k0 + r8 + p * 8;
        tile[r8 + p * 8][c] = (k < K) ? W[(size_t)k * N + n0 + c] : 0.f;
    }
    __syncthreads();
    #pragma unroll
    for (int p = 0; p < 4; p++) {
        int n = n0 + r8 + p * 8;
        WT[(size_t)n * KP + k0 + c] = __float2bfloat16(tile[c][r8 + p * 8]);
    }
}

// Counted-vmcnt double-buffered GEMM (T2 swizzle + T4 counted waits + T5 setprio)
// BM=256 x BN_, 8 waves (2Mx4N). RES_MODE: 0 none, 1 bf16 res[M][N], 2 f32 res[row>>5][N]
// OUTK: 0 = f32 raw scalar (split-K partials), 1 = bf16 leaky, 2 = bf16 raw,
//       3 = bf16 leaky->outb AND bf16 raw->outb2
template<int BN_, int RES_MODE, int OUTK>
__global__ __launch_bounds__(512, 2)
void gemm2ph(const __hip_bfloat16* __restrict__ A, int lda,
             const __hip_bfloat16* __restrict__ Bt,
             const float* __restrict__ bias,
             const __hip_bfloat16* __restrict__ resb,
             const float* __restrict__ resf,
             __hip_bfloat16* __restrict__ outb,
             __hip_bfloat16* __restrict__ outb2,
             float* __restrict__ outf,
             int M, int N, int K, int gx)
{
    constexpr int NF  = BN_ / 64;           // B frags / staging rounds
    constexpr int REL = NF * 16;            // per-wave epilogue row length
    __shared__ __hip_bfloat16 lds[2][(256 + BN_) * BK];

    const int nwg  = gridDim.x;
    const int wgid = xcd_swizzle(blockIdx.x, nwg);
    const int by   = wgid / gx;
    const int bx   = wgid - by * gx;

    const int t    = threadIdx.x;
    const int lane = t & 63;
    const int wv   = t >> 6;
    const int wr   = wv >> 2;               // 0..1
    const int wc   = wv & 3;                // 0..3

    const int row0 = by * 256;
    const int col0 = bx * BN_;

    const int NT = K / BK;
    const int split = blockIdx.y;
    const int kb = (split * NT) / gridDim.y;
    const int ke = ((split + 1) * NT) / gridDim.y;
    float* outfs = outf;
    if (OUTK == 0 && gridDim.y > 1) outfs = outf + (size_t)split * M * N;

    const int srow = t >> 3;                // 0..63
    const int scol = ((t & 7) * 8) ^ ((srow & 7) << 3);  // inverse-swizzled src col
    const int sdst = (t & 7) * 8;                         // linear LDS dest col

    f32x4 acc[8][NF];
    #pragma unroll
    for (int i = 0; i < 8; i++)
        #pragma unroll
        for (int j = 0; j < NF; j++)
            acc[i][j] = f32x4{0.f, 0.f, 0.f, 0.f};

    const int lrow = lane & 15;
    const int lk   = (lane >> 4) * 8;
    const int rxor = (lrow & 7) << 3;

    auto stage = [&](int buf, int kt) {
        const int k0 = kt * BK;
        #pragma unroll
        for (int r = 0; r < 4; ++r)
            gload_lds16(A + (size_t)(row0 + r * 64 + srow) * lda + k0 + scol,
                        &lds[buf][(r * 64 + srow) * BK + sdst]);
        #pragma unroll
        for (int r = 0; r < NF; ++r)
            gload_lds16(Bt + (size_t)(col0 + r * 64 + srow) * K + k0 + scol,
                        &lds[buf][(256 + r * 64 + srow) * BK + sdst]);
    };

    auto compute = [&](int buf) {
        __builtin_amdgcn_s_setprio(1);
        #pragma unroll
        for (int kk = 0; kk < BK; kk += 32) {
            const int kc = (kk + lk) ^ rxor;
            bf16x8 bg[NF];
            #pragma unroll
            for (int j = 0; j < NF; j++)
                bg[j] = *(const bf16x8*)&lds[buf][(256 + wc * REL + j * 16 + lrow) * BK + kc];
            #pragma unroll
            for (int i = 0; i < 8; i++) {
                bf16x8 af = *(const bf16x8*)&lds[buf][(wr * 128 + i * 16 + lrow) * BK + kc];
                #pragma unroll
                for (int j = 0; j < NF; j++)
                    acc[i][j] = __builtin_amdgcn_mfma_f32_16x16x32_bf16(af, bg[j], acc[i][j], 0, 0, 0);
            }
        }
        __builtin_amdgcn_s_setprio(0);
    };

    // ---- pipelined K-loop: counted vmcnt, loads span barriers ----
    int cur = 0;
    stage(0, kb);
    for (int kt = kb; kt < ke - 1; ++kt) {
        stage(cur ^ 1, kt + 1);             // next tile's loads issued first
        if constexpr (NF == 4) asm volatile("s_waitcnt vmcnt(8)" ::: "memory");
        else                   asm volatile("s_waitcnt vmcnt(6)" ::: "memory");
        __builtin_amdgcn_s_barrier();       // tile kt published; kt+1 stays in flight
        __builtin_amdgcn_sched_barrier(0);
        compute(cur);
        __builtin_amdgcn_s_barrier();       // all readers done before overwrite
        cur ^= 1;
    }
    asm volatile("s_waitcnt vmcnt(0)" ::: "memory");
    __builtin_amdgcn_s_barrier();
    compute(cur);

    // ---- epilogue ----
    if constexpr (OUTK == 0) {
        #pragma unroll
        for (int j = 0; j < NF; j++) {
            const int col = col0 + wc * REL + j * 16 + lrow;
            #pragma unroll
            for (int i = 0; i < 8; i++) {
                const int rbase = row0 + wr * 128 + i * 16 + (lane >> 4) * 4;
                #pragma unroll
                for (int r = 0; r < 4; r++)
                    outfs[(size_t)(rbase + r) * N + col] = acc[i][j][r];
            }
        }
    } else {
        __builtin_amdgcn_s_barrier();       // LDS K-buffers free for reuse
        __hip_bfloat16* eb = &lds[0][0] + wv * (128 * REL);
        #pragma unroll
        for (int i = 0; i < 8; i++)
            #pragma unroll
            for (int j = 0; j < NF; j++)
                #pragma unroll
                for (int r = 0; r < 4; r++)
                    eb[(i * 16 + (lane >> 4) * 4 + r) * REL + j * 16 + lrow] =
                        __float2bfloat16(acc[i][j][r]);
        // same-wave LDS ops are in-order: no barrier needed before readback
        constexpr int LPR = REL / 8;        // lanes per row (8 or 4)
        constexpr int RPI = 64 / LPR;       // rows per iteration (8 or 16)
        constexpr int NIT = 128 / RPI;      // iterations (16 or 8)
        const int lrr = lane / LPR;
        const int lcc = (lane % LPR) * 8;
        const int col = col0 + wc * REL + lcc;
        float bvv[8];
        if (bias) {
            float4 b0 = *(const float4*)&bias[col];
            float4 b1 = *(const float4*)&bias[col + 4];
            bvv[0] = b0.x; bvv[1] = b0.y; bvv[2] = b0.z; bvv[3] = b0.w;
            bvv[4] = b1.x; bvv[5] = b1.y; bvv[6] = b1.z; bvv[7] = b1.w;
        } else {
            #pragma unroll
            for (int e = 0; e < 8; e++) bvv[e] = 0.f;
        }
        #pragma unroll
        for (int it = 0; it < NIT; it++) {
            const int rl  = it * RPI + lrr;
            const int row = row0 + wr * 128 + rl;
            bf16x8 v8 = *(bf16x8*)&eb[rl * REL + lcc];
            float vv[8];
            #pragma unroll
            for (int e = 0; e < 8; e++) vv[e] = b2f(v8[e]) + bvv[e];
            if constexpr (RES_MODE == 1) {
                bf16x8 r8 = *(const bf16x8*)&resb[(size_t)row * N + col];
                #pragma unroll
                for (int e = 0; e < 8; e++) vv[e] += b2f(r8[e]);
            }
            if constexpr (RES_MODE == 2) {
                const float* rp = &resf[(size_t)(row >> 5) * N + col];
                float4 r0 = *(const float4*)rp;
                float4 r1 = *(const float4*)(rp + 4);
                vv[0] += r0.x; vv[1] += r0.y; vv[2] += r0.z; vv[3] += r0.w;
                vv[4] += r1.x; vv[5] += r1.y; vv[6] += r1.z; vv[7] += r1.w;
            }
            bf16x8 o1, o2;
            #pragma unroll
            for (int e = 0; e < 8; e++) {
                float lv = vv[e] >= 0.f ? vv[e] : 0.01f * vv[e];
                if constexpr (OUTK == 1) o1[e] = f2bs(lv);
                if constexpr (OUTK == 2) o1[e] = f2bs(vv[e]);
                if constexpr (OUTK == 3) { o1[e] = f2bs(lv); o2[e] = f2bs(vv[e]); }
            }
            *(bf16x8*)&outb[(size_t)row * N + col] = o1;
            if constexpr (OUTK == 3)
                *(bf16x8*)&outb2[(size_t)row * N + col] = o2;
        }
    }
}

// eanchor = sum of 8 split-K partials + be
__global__ __launch_bounds__(256)
void anchor_reduce(const float* __restrict__ part, const float* __restrict__ be,
                   float* __restrict__ out) {
    int i = blockIdx.x * 256 + threadIdx.x;
    if (i >= 512 * 1024) return;
    const int S = 512 * 1024;
    int col = i & 1023;
    float s = be[col];
    #pragma unroll
    for (int p = 0; p < 8; p++) s += part[i + p * S];
    out[i] = s;
}

// out[row] = leaky(h[row]) @ Wd + bd + [0,0,1], h bf16
__global__ __launch_bounds__(256)
void final_head(const __hip_bfloat16* __restrict__ h, const float* __restrict__ Wd,
                const float* __restrict__ bd, float* __restrict__ out)
{
    int row  = blockIdx.x * 4 + (threadIdx.x >> 6);
    int lane = threadIdx.x & 63;
    const __hip_bfloat16* hr = h + (size_t)row * 512;
    bf16x8 v8 = *(const bf16x8*)&hr[lane * 8];
    float s0 = 0.f, s1 = 0.f, s2 = 0.f;
    #pragma unroll
    for (int e = 0; e < 8; e++) {
        float v = b2f(v8[e]);
        v = v >= 0.f ? v : 0.01f * v;
        int k = lane * 8 + e;
        s0 += v * Wd[k * 3 + 0];
        s1 += v * Wd[k * 3 + 1];
        s2 += v * Wd[k * 3 + 2];
    }
    #pragma unroll
    for (int off = 32; off > 0; off >>= 1) {
        s0 += __shfl_down(s0, off);
        s1 += __shfl_down(s1, off);
        s2 += __shfl_down(s2, off);
    }
    if (lane == 0) {
        out[row * 3 + 0] = s0 + bd[0];
        out[row * 3 + 1] = s1 + bd[1];
        out[row * 3 + 2] = s2 + bd[2] + 1.0f;
    }
}

extern "C" void kernel_launch(void* const* d_in, const int* in_sizes, int n_in,
                              void* d_out, int out_size, void* d_ws, size_t ws_size,
                              hipStream_t stream)
{
    const float* features = (const float*)d_in[0];
    const float* We  = (const float*)d_in[1];
    const float* be  = (const float*)d_in[2];
    const float* W1a = (const float*)d_in[3];
    const float* b1a = (const float*)d_in[4];
    const float* W1b = (const float*)d_in[5];
    const float* b1b = (const float*)d_in[6];
    const float* W2a = (const float*)d_in[7];
    const float* b2a = (const float*)d_in[8];
    const float* W2b = (const float*)d_in[9];
    const float* b2b = (const float*)d_in[10];
    const float* Wd  = (const float*)d_in[11];
    const float* bd  = (const float*)d_in[12];
    float* out = (float*)d_out;

    char* ws = (char*)d_ws;
    size_t off = 0;
    auto alloc = [&](size_t bytes) -> char* {
        char* p = ws + off;
        off += (bytes + 255) & ~(size_t)255;
        return p;
    };
    __hip_bfloat16* featbf = (__hip_bfloat16*)alloc(16384ull * 2176 * 2);
    __hip_bfloat16* WeTt   = (__hip_bfloat16*)alloc(1024ull * 2176 * 2);
    __hip_bfloat16* WeTb   = (__hip_bfloat16*)alloc(1024ull * 2176 * 2);
    __hip_bfloat16* W1aT   = (__hip_bfloat16*)alloc(1024ull * 1024 * 2);
    __hip_bfloat16* W1bT   = (__hip_bfloat16*)alloc(512ull * 1024 * 2);
    __hip_bfloat16* W2aT   = (__hip_bfloat16*)alloc(512ull * 512 * 2);
    __hip_bfloat16* W2bT   = (__hip_bfloat16*)alloc(512ull * 512 * 2);
    float* eanchor_part    = (float*)alloc(8ull * 512 * 1024 * 4);
    float* eanchor         = (float*)alloc(512ull * 1024 * 4);
    char* bufA             = alloc(16384ull * 1024 * 2);
    char* bufB             = alloc(16384ull * 1024 * 2);
    __hip_bfloat16* h1b    = (__hip_bfloat16*)alloc(16384ull * 512 * 2);

    __hip_bfloat16* act1   = (__hip_bfloat16*)bufA;
    __hip_bfloat16* act2   = (__hip_bfloat16*)bufB;
    __hip_bfloat16* act3   = (__hip_bfloat16*)bufA;
    __hip_bfloat16* act4   = (__hip_bfloat16*)bufB;
    __hip_bfloat16* hsum_b = (__hip_bfloat16*)bufA;

    // ---- converts ----
    cvt_feat<<<(16384 * 272 + 255) / 256, 256, 0, stream>>>(features, featbf);
    cvt_wt_t<<<68 * 32, 256, 0, stream>>>(We,               WeTt, 2144, 1024, 2176);
    cvt_wt_t<<<68 * 32, 256, 0, stream>>>(We + 2144 * 1024, WeTb, 2144, 1024, 2176);
    cvt_wt_t<<<32 * 32, 256, 0, stream>>>(W1a, W1aT, 1024, 1024, 1024);
    cvt_wt_t<<<32 * 16, 256, 0, stream>>>(W1b, W1bT, 1024, 512, 1024);
    cvt_wt_t<<<16 * 16, 256, 0, stream>>>(W2a, W2aT, 512, 512, 512);
    cvt_wt_t<<<16 * 16, 256, 0, stream>>>(W2b, W2bT, 512, 512, 512);

    // ---- anchor GEMM (split-K=8) ----
    gemm2ph<256, 0, 0><<<dim3(8, 8), 512, 0, stream>>>(
        featbf, 32 * 2176, WeTb, nullptr, nullptr, nullptr,
        nullptr, nullptr, eanchor_part, 512, 1024, 2176, 4);
    anchor_reduce<<<2048, 256, 0, stream>>>(eanchor_part, be, eanchor);

    // ---- L1: act1 = bf16(leaky(feat @ We_top + eanchor_bcast)) ----
    gemm2ph<256, 2, 1><<<dim3(256), 512, 0, stream>>>(
        featbf, 2176, WeTt, nullptr, nullptr, eanchor,
        act1, nullptr, nullptr, 16384, 1024, 2176, 4);

    // ---- L2: act2 = bf16(leaky(act1 @ W1a + b1a)) ----
    gemm2ph<256, 0, 1><<<dim3(256), 512, 0, stream>>>(
        act1, 1024, W1aT, b1a, nullptr, nullptr,
        act2, nullptr, nullptr, 16384, 1024, 1024, 4);

    // ---- L3: h1b = bf16(act2 @ W1b + b1b), act3 = bf16(leaky(h1b)) ----
    gemm2ph<128, 0, 3><<<dim3(256), 512, 0, stream>>>(
        act2, 1024, W1bT, b1b, nullptr, nullptr,
        act3, h1b, nullptr, 16384, 512, 1024, 4);

    // ---- L4: act4 = bf16(leaky(act3 @ W2a + b2a)) ----
    gemm2ph<128, 0, 1><<<dim3(256), 512, 0, stream>>>(
        act3, 512, W2aT, b2a, nullptr, nullptr,
        act4, nullptr, nullptr, 16384, 512, 512, 4);

    // ---- L5: hsum = bf16(act4 @ W2b + b2b + h1b) ----
    gemm2ph<128, 1, 2><<<dim3(256), 512, 0, stream>>>(
        act4, 512, W2bT, b2b, h1b, nullptr,
        hsum_b, nullptr, nullptr, 16384, 512, 512, 4);

    // ---- head ----
    final_head<<<4096, 256, 0, stream>>>(hsum_b, Wd, bd, out);
}